// Round 4
// baseline (267.605 us; speedup 1.0000x reference)
//
#include <hip/hip_runtime.h>
#include <hip/hip_fp16.h>

#define NFEAT 17
#define HH 8
#define BSZ 256
#define TSZ 512
#define SUMD 59
#define NCH (BSZ*NFEAT)      // 4352 chains
#define NTP (TSZ/2)          // 256 timestep-pairs

__constant__ int c_dim[NFEAT] = {2,8,12,13,12,1,1,1,1,1,1,1,1,1,1,1,1};
__constant__ int c_off[NFEAT] = {0,2,10,22,35,47,48,49,50,51,52,53,54,55,56,57,58};

// ---------- Kernel T: transpose W_ih [f][g][d] -> wT [f][d][g] (g contiguous, s_load friendly) ----------
__global__ __launch_bounds__(256) void transpose_wih(const float* __restrict__ Wih,
                                                     float* __restrict__ wT) {
  int i = blockIdx.x * 256 + threadIdx.x;
  if (i < NFEAT * 312) {
    int f = i / 312, r = i - f * 312, d = r / 24, g = r - d * 24;
    wT[i] = Wih[f * 312 + g * 13 + d];
  }
}

// ---------- Kernel A: gx = x_pad . W_ih^T + b_ih, fp16, [chain][tp][j][6 halves] ----------
#define GT_THREADS 128
#define SLAB_T 256                  // timesteps staged per block
#define SLAB_DW (SLAB_T*SUMD)       // 15104 dwords = 60416 B
#define STG_STRIDE 28               // out-stage row stride (dwords): 16B-aligned, breaks bank alias

template<int D>
__device__ __forceinline__ void feat_accum(const float* __restrict__ xr0,
                                           const float* __restrict__ xr1,
                                           const float* __restrict__ wf,
                                           const float* __restrict__ bf,
                                           float* a0, float* a1) {
  float x0[D], x1[D];
  #pragma unroll
  for (int d = 0; d < D; ++d) { x0[d] = xr0[d]; x1[d] = xr1[d]; }
  #pragma unroll
  for (int g = 0; g < 24; ++g) { float bb = bf[g]; a0[g] = bb; a1[g] = bb; }
  #pragma unroll
  for (int d = 0; d < D; ++d) {
    #pragma unroll
    for (int g = 0; g < 24; ++g) {
      float w = wf[d * 24 + g];        // wave-uniform -> scalar load
      a0[g] = fmaf(x0[d], w, a0[g]);
      a1[g] = fmaf(x1[d], w, a1[g]);
    }
  }
}

__global__ __launch_bounds__(GT_THREADS) void gates_kernel(const float* __restrict__ x,
                                                           const float* __restrict__ wT,
                                                           const float* __restrict__ bih,
                                                           __half* __restrict__ gx) {
  __shared__ float slab[SLAB_DW];                 // x slab, unpadded (2-way bank alias = free)
  __shared__ unsigned stg[GT_THREADS * STG_STRIDE]; // per-f output staging (14.3 KB)
  int tid = threadIdx.x;
  int b = blockIdx.x >> 1, half = blockIdx.x & 1;

  // coalesced slab load: 15104 dwords as 7552 uint2
  {
    const uint2* src = (const uint2*)(x + ((size_t)b * TSZ + half * SLAB_T) * SUMD);
    uint2* dst = (uint2*)slab;
    for (int k = 0; k < SLAB_DW / 2 / GT_THREADS; ++k)   // 59 iters
      dst[tid + k * GT_THREADS] = src[tid + k * GT_THREADS];
  }
  __syncthreads();

  const float* xr0 = slab + (2 * tid) * SUMD;
  const float* xr1 = xr0 + SUMD;
  unsigned* gxw = (unsigned*)gx;

  #pragma unroll 1
  for (int f = 0; f < NFEAT; ++f) {
    int D = c_dim[f], off = c_off[f];
    const float* wf = wT + f * 312;
    const float* bf = bih + f * 24;
    float a0[24], a1[24];
    switch (D) {
      case 13: feat_accum<13>(xr0 + off, xr1 + off, wf, bf, a0, a1); break;
      case 12: feat_accum<12>(xr0 + off, xr1 + off, wf, bf, a0, a1); break;
      case 8:  feat_accum<8>(xr0 + off, xr1 + off, wf, bf, a0, a1); break;
      case 2:  feat_accum<2>(xr0 + off, xr1 + off, wf, bf, a0, a1); break;
      default: feat_accum<1>(xr0 + off, xr1 + off, wf, bf, a0, a1); break;
    }
    union { __half hs[48]; uint4 q[6]; } u;
    #pragma unroll
    for (int j = 0; j < 8; ++j) {
      u.hs[j * 6 + 0] = __float2half(a0[j]);        // r_j, t0
      u.hs[j * 6 + 1] = __float2half(a0[8 + j]);    // z_j, t0
      u.hs[j * 6 + 2] = __float2half(a0[16 + j]);   // n_j, t0
      u.hs[j * 6 + 3] = __float2half(a1[j]);        // r_j, t1
      u.hs[j * 6 + 4] = __float2half(a1[8 + j]);
      u.hs[j * 6 + 5] = __float2half(a1[16 + j]);
    }
    // stage 24 dwords, 16B-aligned rows
    unsigned* srow = stg + tid * STG_STRIDE;
    #pragma unroll
    for (int q = 0; q < 6; ++q) *(uint4*)(srow + q * 4) = u.q[q];
    __syncthreads();
    // dense write: 3072 dwords per (b,f,half), thread q-strided
    size_t basedw = ((size_t)(b * NFEAT + f) * NTP + half * (SLAB_T / 2)) * 24;
    #pragma unroll
    for (int q = 0; q < 6; ++q) {
      int idx = q * 512 + tid * 4;
      int tp = idx / 24, c = idx - tp * 24;       // c is a multiple of 4
      uint4 v = *(const uint4*)(stg + tp * STG_STRIDE + c);
      *(uint4*)(gxw + basedw + idx) = v;
    }
    __syncthreads();
  }
}

// ---------- Kernel B: sequential GRU scan, 8 lanes/chain, DPP all-gather ----------
__device__ __forceinline__ float fexp2(float v) { return __builtin_amdgcn_exp2f(v); }
__device__ __forceinline__ float frcp(float v)  { return __builtin_amdgcn_rcpf(v); }
__device__ __forceinline__ float h2f(unsigned s) {
  __half_raw hr; hr.x = (unsigned short)s; return __half2float(__half(hr));
}
__device__ __forceinline__ uint3 ldu3(const unsigned* __restrict__ p) {
  uint3 v; v.x = p[0]; v.y = p[1]; v.z = p[2]; return v;
}

// DPP helpers: ctrl/bank masks are compile-time literals via macro expansion
#define DPPF(SRC, CTRL, BMASK) \
  __int_as_float(__builtin_amdgcn_update_dpp(0, __float_as_int(SRC), (CTRL), 0xF, (BMASK), false))
#define DPPF2(OLD, SRC, CTRL, BMASK) \
  __int_as_float(__builtin_amdgcn_update_dpp(__float_as_int(OLD), __float_as_int(SRC), (CTRL), 0xF, (BMASK), false))

__global__ __launch_bounds__(64) void scan_kernel(const __half* __restrict__ gx,
                                                  const float* __restrict__ Whh,
                                                  const float* __restrict__ bhh,
                                                  float* __restrict__ out) {
  int tid = threadIdx.x;
  int j = tid & 7;                          // hidden unit owned by this lane
  int chain = blockIdx.x * 8 + (tid >> 3);
  int b = chain / NFEAT, f = chain - b * NFEAT;

  // weights xor-permuted: w[m] multiplies hx[m] = h_{j^m}
  const float* wb = Whh + f * 192;
  float wr[8], wz[8], wn[8];
  #pragma unroll
  for (int m = 0; m < 8; ++m) {
    int k = j ^ m;
    wr[m] = wb[j * 8 + k];
    wz[m] = wb[64 + j * 8 + k];
    wn[m] = wb[128 + j * 8 + k];
  }
  float br = bhh[f * 24 + j], bz = bhh[f * 24 + 8 + j], bn = bhh[f * 24 + 16 + j];

  const unsigned* gp = (const unsigned*)gx + (size_t)chain * (NTP * 24) + j * 3;
  float* op = out + ((size_t)b * TSZ * NFEAT + f) * HH + j;

  float hx0 = 0.f, hx1 = 0.f, hx2 = 0.f, hx3 = 0.f, hx4 = 0.f, hx5 = 0.f, hx6 = 0.f, hx7 = 0.f;

  const float NL2E = -1.4426950408889634f;    // -log2(e)
  const float N2L2E = -2.885390081777927f;    // -2*log2(e)

  // xor-4 exchange within each 8-lane group (DPP row = 16 lanes):
  //   banks 0,2 (lanes 0-3, 8-11) read lane i+4  -> row_shl:4 (0x104), bank_mask 0x5
  //   banks 1,3 (lanes 4-7,12-15) read lane i-4  -> row_shr:4 (0x114), bank_mask 0xA
  #define SSTEP(GXR, GXZ, GXN) do {                                                   \
    float pr = (fmaf(hx0, wr[0], hx1 * wr[1]) + fmaf(hx2, wr[2], hx3 * wr[3]))        \
             + (fmaf(hx4, wr[4], hx5 * wr[5]) + fmaf(hx6, wr[6], hx7 * wr[7]));       \
    float pz = (fmaf(hx0, wz[0], hx1 * wz[1]) + fmaf(hx2, wz[2], hx3 * wz[3]))        \
             + (fmaf(hx4, wz[4], hx5 * wz[5]) + fmaf(hx6, wz[6], hx7 * wz[7]));       \
    float pn = (fmaf(hx0, wn[0], hx1 * wn[1]) + fmaf(hx2, wn[2], hx3 * wn[3]))        \
             + (fmaf(hx4, wn[4], hx5 * wn[5]) + fmaf(hx6, wn[6], hx7 * wn[7]));       \
    float rr = frcp(1.f + fexp2(((GXR) + br + pr) * NL2E));                           \
    float zz = frcp(1.f + fexp2(((GXZ) + bz + pz) * NL2E));                           \
    float ee = fexp2(((GXN) + rr * (bn + pn)) * N2L2E);                               \
    float nn = (1.f - ee) * frcp(1.f + ee);                                           \
    hx0 = fmaf(zz, hx0 - nn, nn);                                                     \
    *op = hx0; op += NFEAT * HH;                                                      \
    hx1 = DPPF(hx0, 0xB1, 0xF);               /* h_{j^1}: quad_perm [1,0,3,2] */      \
    hx2 = DPPF(hx0, 0x4E, 0xF);               /* h_{j^2}: quad_perm [2,3,0,1] */      \
    hx3 = DPPF(hx1, 0x4E, 0xF);               /* h_{j^3} */                           \
    { float t4 = DPPF(hx0, 0x104, 0x5); hx4 = DPPF2(t4, hx0, 0x114, 0xA); }           \
    { float t5 = DPPF(hx1, 0x104, 0x5); hx5 = DPPF2(t5, hx1, 0x114, 0xA); }           \
    { float t6 = DPPF(hx2, 0x104, 0x5); hx6 = DPPF2(t6, hx2, 0x114, 0xA); }           \
    { float t7 = DPPF(hx3, 0x104, 0x5); hx7 = DPPF2(t7, hx3, 0x114, 0xA); }           \
  } while (0)

  uint3 P[8];
  #pragma unroll
  for (int i = 0; i < 8; ++i) P[i] = ldu3(gp + i * 24);

  for (int tpb = 0; tpb < NTP; tpb += 8) {
    #pragma unroll
    for (int i = 0; i < 8; ++i) {
      uint3 U = P[i];
      int t = tpb + 8 + i; t = t < NTP ? t : NTP - 1;   // tail refetch, harmless
      P[i] = ldu3(gp + (size_t)t * 24);
      SSTEP(h2f(U.x & 0xffff), h2f(U.x >> 16), h2f(U.y & 0xffff));
      SSTEP(h2f(U.y >> 16), h2f(U.z & 0xffff), h2f(U.z >> 16));
    }
  }
  #undef SSTEP
}

extern "C" void kernel_launch(void* const* d_in, const int* in_sizes, int n_in,
                              void* d_out, int out_size, void* d_ws, size_t ws_size,
                              hipStream_t stream) {
  const float* x   = (const float*)d_in[0];
  const float* Wih = (const float*)d_in[1];
  const float* Whh = (const float*)d_in[2];
  const float* bih = (const float*)d_in[3];
  const float* bhh = (const float*)d_in[4];
  float* out = (float*)d_out;
  __half* gxws = (__half*)d_ws;            // NCH*NTP*96 B ~= 102 MB

  // W_ih transpose scratch in the tail of d_out; consumed by gates before
  // scan overwrites every element of d_out (stream-ordered).
  float* wT = out + ((size_t)out_size - NFEAT * 312);

  hipLaunchKernelGGL(transpose_wih, dim3(21), dim3(256), 0, stream, Wih, wT);
  hipLaunchKernelGGL(gates_kernel, dim3(BSZ * 2), dim3(GT_THREADS), 0, stream, x, wT, bih, gxws);
  hipLaunchKernelGGL(scan_kernel, dim3(NCH / 8), dim3(64), 0, stream, gxws, Whh, bhh, out);
}